// Round 1
// baseline (178.260 us; speedup 1.0000x reference)
//
#include <hip/hip_runtime.h>

#define DXC     0.5f
#define NSTEPS  8
#define BB      8
#define HH      512
#define WW      512
#define NPIX    (HH * WW)              // 262144
#define NTHREADS (BB * NPIX)           // 2097152
#define TOTAL_COUNT 37748736.0         // (NSTEPS+1) * B * 2 * H * W

// Bilinear interp of a 2-channel field (planes vf0, vf1 of HxW) at (px,py),
// clipped to the domain exactly as the reference does.
__device__ __forceinline__ float2 bilerp2(const float* __restrict__ vf0,
                                          const float* __restrict__ vf1,
                                          float px, float py) {
    float x = fminf(fmaxf(px, 0.0f), (float)(WW - 1));
    float y = fminf(fmaxf(py, 0.0f), (float)(HH - 1));
    float x0f = floorf(x);
    float y0f = floorf(y);
    float wx = x - x0f;
    float wy = y - y0f;
    int x0 = (int)x0f;
    int y0 = (int)y0f;
    int x1 = min(x0 + 1, WW - 1);
    int y1 = min(y0 + 1, HH - 1);
    int i00 = y0 * WW + x0;
    int i01 = y0 * WW + x1;
    int i10 = y1 * WW + x0;
    int i11 = y1 * WW + x1;
    float a00 = vf0[i00], a01 = vf0[i01], a10 = vf0[i10], a11 = vf0[i11];
    float b00 = vf1[i00], b01 = vf1[i01], b10 = vf1[i10], b11 = vf1[i11];
    float omwx = 1.0f - wx;
    float omwy = 1.0f - wy;
    float vx = (a00 * omwx + a01 * wx) * omwy + (a10 * omwx + a11 * wx) * wy;
    float vy = (b00 * omwx + b01 * wx) * omwy + (b10 * omwx + b11 * wx) * wy;
    return make_float2(vx, vy);
}

__global__ __launch_bounds__(256) void ivp_loss_kernel(
        const float* __restrict__ vf_pred,
        const float* __restrict__ vf_true,
        double* __restrict__ ws_sum) {
    int tid = blockIdx.x * blockDim.x + threadIdx.x;
    float acc = 0.0f;
    if (tid < NTHREADS) {
        int b   = tid >> 18;            // / (512*512)
        int pix = tid & (NPIX - 1);
        int y   = pix >> 9;
        int x   = pix & (WW - 1);

        const float* tp0 = vf_pred + (size_t)b * 2 * NPIX;  // pred channel 0 (vx)
        const float* tp1 = tp0 + NPIX;                      // pred channel 1 (vy)
        const float* tt0 = vf_true + (size_t)b * 2 * NPIX;  // true channel 0
        const float* tt1 = tt0 + NPIX;                      // true channel 1

        float ptx = (float)x, pty = (float)y;   // true-traj position
        float ppx = ptx,      ppy = pty;        // pred-traj position

        #pragma unroll
        for (int s = 0; s < NSTEPS; ++s) {
            float2 vt = bilerp2(tt0, tt1, ptx, pty);
            float2 vp = bilerp2(tp0, tp1, ppx, ppy);
            ptx += DXC * vt.x;
            pty += DXC * vt.y;
            ppx += DXC * vp.x;
            ppy += DXC * vp.y;
            float dx = ptx - ppx;
            float dy = pty - ppy;
            acc += dx * dx + dy * dy;
        }
    }

    // Reduce: wave-64 shuffle in double, then LDS across the 4 waves.
    double dacc = (double)acc;
    #pragma unroll
    for (int off = 32; off > 0; off >>= 1)
        dacc += __shfl_down(dacc, off, 64);

    __shared__ double sred[4];
    int lane = threadIdx.x & 63;
    int wid  = threadIdx.x >> 6;
    if (lane == 0) sred[wid] = dacc;
    __syncthreads();
    if (threadIdx.x == 0) {
        double t = sred[0] + sred[1] + sred[2] + sred[3];
        atomicAdd(ws_sum, t);
    }
}

__global__ void ivp_finalize_kernel(const double* __restrict__ ws_sum,
                                    float* __restrict__ out) {
    out[0] = (float)(ws_sum[0] / TOTAL_COUNT);
}

extern "C" void kernel_launch(void* const* d_in, const int* in_sizes, int n_in,
                              void* d_out, int out_size, void* d_ws, size_t ws_size,
                              hipStream_t stream) {
    const float* vf_pred = (const float*)d_in[0];
    const float* vf_true = (const float*)d_in[1];
    float* out = (float*)d_out;
    double* ws_sum = (double*)d_ws;

    hipMemsetAsync(ws_sum, 0, sizeof(double), stream);

    int block = 256;
    int grid  = NTHREADS / block;  // 8192
    ivp_loss_kernel<<<grid, block, 0, stream>>>(vf_pred, vf_true, ws_sum);
    ivp_finalize_kernel<<<1, 1, 0, stream>>>(ws_sum, out);
}

// Round 2
// 155.174 us; speedup vs baseline: 1.1488x; 1.1488x over previous
//
#include <hip/hip_runtime.h>

#define DXC     0.5f
#define NSTEPS  8
#define BB      8
#define HH      512
#define WW      512
#define NPIX    (HH * WW)              // 262144
#define NTHREADS (BB * NPIX)           // 2097152
#define TOTAL_COUNT 37748736.0         // (NSTEPS+1) * B * 2 * H * W

// ---------------------------------------------------------------------------
// Prep: build duplicated-interleaved layout per field:
//   dup[b][y][x] = float4{ vx(x), vy(x), vx(min(x+1,W-1)), vy(min(x+1,W-1)) }
// 16B-aligned so one bilerp corner-row = one global_load_dwordx4.
// ---------------------------------------------------------------------------
__global__ __launch_bounds__(256) void ivp_prep_kernel(
        const float* __restrict__ vf_pred,
        const float* __restrict__ vf_true,
        float4* __restrict__ dupP,
        float4* __restrict__ dupT) {
    int tid = blockIdx.x * blockDim.x + threadIdx.x;   // 0..NTHREADS-1
    int b   = tid >> 18;
    int pix = tid & (NPIX - 1);
    int x   = pix & (WW - 1);
    int xn  = min(x + 1, WW - 1);
    int rowbase = pix - x;                             // y*WW

    const float* p0 = vf_pred + (size_t)b * 2 * NPIX;
    const float* p1 = p0 + NPIX;
    const float* t0 = vf_true + (size_t)b * 2 * NPIX;
    const float* t1 = t0 + NPIX;

    dupP[tid] = make_float4(p0[pix], p1[pix], p0[rowbase + xn], p1[rowbase + xn]);
    dupT[tid] = make_float4(t0[pix], t1[pix], t0[rowbase + xn], t1[rowbase + xn]);
}

// Bilinear interp from the duplicated layout: 2 float4 loads total.
__device__ __forceinline__ float2 bilerp_dup(const float4* __restrict__ f,
                                             float px, float py) {
    float x = fminf(fmaxf(px, 0.0f), (float)(WW - 1));
    float y = fminf(fmaxf(py, 0.0f), (float)(HH - 1));
    float x0f = floorf(x);
    float y0f = floorf(y);
    float wx = x - x0f;
    float wy = y - y0f;
    int x0 = (int)x0f;
    int y0 = (int)y0f;
    int y1 = min(y0 + 1, HH - 1);
    float4 r0 = f[y0 * WW + x0];
    float4 r1 = f[y1 * WW + x0];
    float omwx = 1.0f - wx;
    float omwy = 1.0f - wy;
    float vx = (r0.x * omwx + r0.z * wx) * omwy + (r1.x * omwx + r1.z * wx) * wy;
    float vy = (r0.y * omwx + r0.w * wx) * omwy + (r1.y * omwx + r1.w * wx) * wy;
    return make_float2(vx, vy);
}

// Main: 2 pixels per thread (4 independent Euler chains) for MLP.
__global__ __launch_bounds__(256) void ivp_main_kernel(
        const float4* __restrict__ dupP,
        const float4* __restrict__ dupT,
        double* __restrict__ ws_sum) {
    int tid = blockIdx.x * blockDim.x + threadIdx.x;   // 0..NTHREADS/2-1
    int pA = tid;
    int pB = tid + NTHREADS / 2;

    int bA = pA >> 18, pixA = pA & (NPIX - 1);
    int bB = pB >> 18, pixB = pB & (NPIX - 1);

    const float4* fPA = dupP + (size_t)bA * NPIX;
    const float4* fTA = dupT + (size_t)bA * NPIX;
    const float4* fPB = dupP + (size_t)bB * NPIX;
    const float4* fTB = dupT + (size_t)bB * NPIX;

    float aTx = (float)(pixA & (WW - 1)), aTy = (float)(pixA >> 9);
    float aPx = aTx, aPy = aTy;
    float bTx = (float)(pixB & (WW - 1)), bTy = (float)(pixB >> 9);
    float bPx = bTx, bPy = bTy;

    float acc = 0.0f;
    #pragma unroll
    for (int s = 0; s < NSTEPS; ++s) {
        float2 vTA = bilerp_dup(fTA, aTx, aTy);
        float2 vPA = bilerp_dup(fPA, aPx, aPy);
        float2 vTB = bilerp_dup(fTB, bTx, bTy);
        float2 vPB = bilerp_dup(fPB, bPx, bPy);
        aTx += DXC * vTA.x;  aTy += DXC * vTA.y;
        aPx += DXC * vPA.x;  aPy += DXC * vPA.y;
        bTx += DXC * vTB.x;  bTy += DXC * vTB.y;
        bPx += DXC * vPB.x;  bPy += DXC * vPB.y;
        float dxA = aTx - aPx, dyA = aTy - aPy;
        float dxB = bTx - bPx, dyB = bTy - bPy;
        acc += dxA * dxA + dyA * dyA + dxB * dxB + dyB * dyB;
    }

    // Wave-64 shuffle reduce in double, then LDS across 4 waves.
    double dacc = (double)acc;
    #pragma unroll
    for (int off = 32; off > 0; off >>= 1)
        dacc += __shfl_down(dacc, off, 64);

    __shared__ double sred[4];
    int lane = threadIdx.x & 63;
    int wid  = threadIdx.x >> 6;
    if (lane == 0) sred[wid] = dacc;
    __syncthreads();
    if (threadIdx.x == 0) {
        double t = sred[0] + sred[1] + sred[2] + sred[3];
        atomicAdd(ws_sum, t);
    }
}

// ---------------------------------------------------------------------------
// Fallback (R1 kernel) if ws_size can't hold the duplicated layout.
// ---------------------------------------------------------------------------
__device__ __forceinline__ float2 bilerp2(const float* __restrict__ vf0,
                                          const float* __restrict__ vf1,
                                          float px, float py) {
    float x = fminf(fmaxf(px, 0.0f), (float)(WW - 1));
    float y = fminf(fmaxf(py, 0.0f), (float)(HH - 1));
    float x0f = floorf(x);
    float y0f = floorf(y);
    float wx = x - x0f;
    float wy = y - y0f;
    int x0 = (int)x0f;
    int y0 = (int)y0f;
    int x1 = min(x0 + 1, WW - 1);
    int y1 = min(y0 + 1, HH - 1);
    int i00 = y0 * WW + x0;
    int i01 = y0 * WW + x1;
    int i10 = y1 * WW + x0;
    int i11 = y1 * WW + x1;
    float a00 = vf0[i00], a01 = vf0[i01], a10 = vf0[i10], a11 = vf0[i11];
    float b00 = vf1[i00], b01 = vf1[i01], b10 = vf1[i10], b11 = vf1[i11];
    float omwx = 1.0f - wx;
    float omwy = 1.0f - wy;
    float vx = (a00 * omwx + a01 * wx) * omwy + (a10 * omwx + a11 * wx) * wy;
    float vy = (b00 * omwx + b01 * wx) * omwy + (b10 * omwx + b11 * wx) * wy;
    return make_float2(vx, vy);
}

__global__ __launch_bounds__(256) void ivp_loss_fallback_kernel(
        const float* __restrict__ vf_pred,
        const float* __restrict__ vf_true,
        double* __restrict__ ws_sum) {
    int tid = blockIdx.x * blockDim.x + threadIdx.x;
    float acc = 0.0f;
    {
        int b   = tid >> 18;
        int pix = tid & (NPIX - 1);
        int y   = pix >> 9;
        int x   = pix & (WW - 1);
        const float* tp0 = vf_pred + (size_t)b * 2 * NPIX;
        const float* tp1 = tp0 + NPIX;
        const float* tt0 = vf_true + (size_t)b * 2 * NPIX;
        const float* tt1 = tt0 + NPIX;
        float ptx = (float)x, pty = (float)y;
        float ppx = ptx,      ppy = pty;
        #pragma unroll
        for (int s = 0; s < NSTEPS; ++s) {
            float2 vt = bilerp2(tt0, tt1, ptx, pty);
            float2 vp = bilerp2(tp0, tp1, ppx, ppy);
            ptx += DXC * vt.x;  pty += DXC * vt.y;
            ppx += DXC * vp.x;  ppy += DXC * vp.y;
            float dx = ptx - ppx;
            float dy = pty - ppy;
            acc += dx * dx + dy * dy;
        }
    }
    double dacc = (double)acc;
    #pragma unroll
    for (int off = 32; off > 0; off >>= 1)
        dacc += __shfl_down(dacc, off, 64);
    __shared__ double sred[4];
    int lane = threadIdx.x & 63;
    int wid  = threadIdx.x >> 6;
    if (lane == 0) sred[wid] = dacc;
    __syncthreads();
    if (threadIdx.x == 0) {
        double t = sred[0] + sred[1] + sred[2] + sred[3];
        atomicAdd(ws_sum, t);
    }
}

__global__ void ivp_finalize_kernel(const double* __restrict__ ws_sum,
                                    float* __restrict__ out) {
    out[0] = (float)(ws_sum[0] / TOTAL_COUNT);
}

extern "C" void kernel_launch(void* const* d_in, const int* in_sizes, int n_in,
                              void* d_out, int out_size, void* d_ws, size_t ws_size,
                              hipStream_t stream) {
    const float* vf_pred = (const float*)d_in[0];
    const float* vf_true = (const float*)d_in[1];
    float* out = (float*)d_out;

    double* ws_sum = (double*)d_ws;
    hipMemsetAsync(ws_sum, 0, sizeof(double), stream);

    const size_t dup_bytes = (size_t)NTHREADS * sizeof(float4);     // 32 MB per field
    const size_t need = 1024 + 2 * dup_bytes;                        // 64 MB + header

    if (ws_size >= need) {
        float4* dupP = (float4*)((char*)d_ws + 1024);
        float4* dupT = (float4*)((char*)d_ws + 1024 + dup_bytes);
        ivp_prep_kernel<<<NTHREADS / 256, 256, 0, stream>>>(vf_pred, vf_true, dupP, dupT);
        ivp_main_kernel<<<NTHREADS / 2 / 256, 256, 0, stream>>>(dupP, dupT, ws_sum);
    } else {
        ivp_loss_fallback_kernel<<<NTHREADS / 256, 256, 0, stream>>>(vf_pred, vf_true, ws_sum);
    }
    ivp_finalize_kernel<<<1, 1, 0, stream>>>(ws_sum, out);
}

// Round 3
// 83.384 us; speedup vs baseline: 2.1378x; 1.8610x over previous
//
#include <hip/hip_runtime.h>
#include <hip/hip_fp16.h>

#define DXC     0.5f
#define NSTEPS  8
#define BB      8
#define HH      512
#define WW      512
#define NPIX    (HH * WW)              // 262144
#define NTHREADS (BB * NPIX)           // 2097152
#define TOTAL_COUNT 37748736.0         // (NSTEPS+1) * B * 2 * H * W

// ---------------------------------------------------------------------------
// Prep: duplicated-interleaved fp16 layout per field (8 B per pixel):
//   dup[b][y][x] = uint2{ h2(vx(x),vy(x)), h2(vx(x+1),vy(x+1)) }  (x+1 clamped)
// One bilerp corner-row = one global_load_dwordx2.
// ---------------------------------------------------------------------------
__device__ __forceinline__ unsigned packh2(float a, float b) {
    __half2 h = __floats2half2_rn(a, b);
    return __builtin_bit_cast(unsigned, h);
}

__global__ __launch_bounds__(256) void ivp_prep_kernel(
        const float* __restrict__ vf_pred,
        const float* __restrict__ vf_true,
        uint2* __restrict__ dupP,
        uint2* __restrict__ dupT) {
    int tid = blockIdx.x * blockDim.x + threadIdx.x;   // 0..NTHREADS-1
    int b   = tid >> 18;
    int pix = tid & (NPIX - 1);
    int x   = pix & (WW - 1);
    int xn  = min(x + 1, WW - 1);
    int rowbase = pix - x;                             // y*WW

    const float* p0 = vf_pred + (size_t)b * 2 * NPIX;
    const float* p1 = p0 + NPIX;
    const float* t0 = vf_true + (size_t)b * 2 * NPIX;
    const float* t1 = t0 + NPIX;

    dupP[tid] = make_uint2(packh2(p0[pix], p1[pix]),
                           packh2(p0[rowbase + xn], p1[rowbase + xn]));
    dupT[tid] = make_uint2(packh2(t0[pix], t1[pix]),
                           packh2(t0[rowbase + xn], t1[rowbase + xn]));
}

// Bilinear interp from the fp16 dup layout: 2x 8B loads, fp32 math.
__device__ __forceinline__ float2 bilerp_duph(const uint2* __restrict__ f,
                                              float px, float py) {
    float x = fminf(fmaxf(px, 0.0f), (float)(WW - 1));
    float y = fminf(fmaxf(py, 0.0f), (float)(HH - 1));
    float x0f = floorf(x);
    float y0f = floorf(y);
    float wx = x - x0f;
    float wy = y - y0f;
    int x0 = (int)x0f;
    int y0 = (int)y0f;
    int y1 = min(y0 + 1, HH - 1);
    uint2 r0 = f[y0 * WW + x0];
    uint2 r1 = f[y1 * WW + x0];
    float2 a0 = __half22float2(__builtin_bit_cast(__half2, r0.x)); // (vx,vy) @ (y0,x0)
    float2 a1 = __half22float2(__builtin_bit_cast(__half2, r0.y)); // (vx,vy) @ (y0,x1)
    float2 b0 = __half22float2(__builtin_bit_cast(__half2, r1.x)); // (y1,x0)
    float2 b1 = __half22float2(__builtin_bit_cast(__half2, r1.y)); // (y1,x1)
    float omwx = 1.0f - wx;
    float omwy = 1.0f - wy;
    float vx = (a0.x * omwx + a1.x * wx) * omwy + (b0.x * omwx + b1.x * wx) * wy;
    float vy = (a0.y * omwx + a1.y * wx) * omwy + (b0.y * omwx + b1.y * wx) * wy;
    return make_float2(vx, vy);
}

// Main: 2 pixels per thread (4 independent Euler chains). Chunked XCD swizzle
// so each XCD owns a contiguous pixel range (L2 locality across steps).
__global__ __launch_bounds__(256) void ivp_main_kernel(
        const uint2* __restrict__ dupP,
        const uint2* __restrict__ dupT,
        double* __restrict__ ws_sum) {
    // 4096 blocks; XCD k (dispatch round-robin bid%8) gets logical chunk k.
    int bid = blockIdx.x;
    int lb  = (bid & 7) * (4096 / 8) + (bid >> 3);
    int tid = lb * blockDim.x + threadIdx.x;           // 0..NTHREADS/2-1

    int pA = tid;
    int pB = tid + NTHREADS / 2;

    int bA = pA >> 18, pixA = pA & (NPIX - 1);
    int bB = pB >> 18, pixB = pB & (NPIX - 1);

    const uint2* fPA = dupP + (size_t)bA * NPIX;
    const uint2* fTA = dupT + (size_t)bA * NPIX;
    const uint2* fPB = dupP + (size_t)bB * NPIX;
    const uint2* fTB = dupT + (size_t)bB * NPIX;

    float aTx = (float)(pixA & (WW - 1)), aTy = (float)(pixA >> 9);
    float aPx = aTx, aPy = aTy;
    float bTx = (float)(pixB & (WW - 1)), bTy = (float)(pixB >> 9);
    float bPx = bTx, bPy = bTy;

    float acc = 0.0f;
    #pragma unroll
    for (int s = 0; s < NSTEPS; ++s) {
        float2 vTA = bilerp_duph(fTA, aTx, aTy);
        float2 vPA = bilerp_duph(fPA, aPx, aPy);
        float2 vTB = bilerp_duph(fTB, bTx, bTy);
        float2 vPB = bilerp_duph(fPB, bPx, bPy);
        aTx += DXC * vTA.x;  aTy += DXC * vTA.y;
        aPx += DXC * vPA.x;  aPy += DXC * vPA.y;
        bTx += DXC * vTB.x;  bTy += DXC * vTB.y;
        bPx += DXC * vPB.x;  bPy += DXC * vPB.y;
        float dxA = aTx - aPx, dyA = aTy - aPy;
        float dxB = bTx - bPx, dyB = bTy - bPy;
        acc += dxA * dxA + dyA * dyA + dxB * dxB + dyB * dyB;
    }

    // Wave-64 shuffle reduce in double, then LDS across 4 waves.
    double dacc = (double)acc;
    #pragma unroll
    for (int off = 32; off > 0; off >>= 1)
        dacc += __shfl_down(dacc, off, 64);

    __shared__ double sred[4];
    int lane = threadIdx.x & 63;
    int wid  = threadIdx.x >> 6;
    if (lane == 0) sred[wid] = dacc;
    __syncthreads();
    if (threadIdx.x == 0) {
        double t = sred[0] + sred[1] + sred[2] + sred[3];
        atomicAdd(ws_sum, t);
    }
}

// ---------------------------------------------------------------------------
// Fallback (R1 kernel) if ws_size can't hold the duplicated layout.
// ---------------------------------------------------------------------------
__device__ __forceinline__ float2 bilerp2(const float* __restrict__ vf0,
                                          const float* __restrict__ vf1,
                                          float px, float py) {
    float x = fminf(fmaxf(px, 0.0f), (float)(WW - 1));
    float y = fminf(fmaxf(py, 0.0f), (float)(HH - 1));
    float x0f = floorf(x);
    float y0f = floorf(y);
    float wx = x - x0f;
    float wy = y - y0f;
    int x0 = (int)x0f;
    int y0 = (int)y0f;
    int x1 = min(x0 + 1, WW - 1);
    int y1 = min(y0 + 1, HH - 1);
    int i00 = y0 * WW + x0;
    int i01 = y0 * WW + x1;
    int i10 = y1 * WW + x0;
    int i11 = y1 * WW + x1;
    float a00 = vf0[i00], a01 = vf0[i01], a10 = vf0[i10], a11 = vf0[i11];
    float b00 = vf1[i00], b01 = vf1[i01], b10 = vf1[i10], b11 = vf1[i11];
    float omwx = 1.0f - wx;
    float omwy = 1.0f - wy;
    float vx = (a00 * omwx + a01 * wx) * omwy + (a10 * omwx + a11 * wx) * wy;
    float vy = (b00 * omwx + b01 * wx) * omwy + (b10 * omwx + b11 * wx) * wy;
    return make_float2(vx, vy);
}

__global__ __launch_bounds__(256) void ivp_loss_fallback_kernel(
        const float* __restrict__ vf_pred,
        const float* __restrict__ vf_true,
        double* __restrict__ ws_sum) {
    int tid = blockIdx.x * blockDim.x + threadIdx.x;
    float acc = 0.0f;
    {
        int b   = tid >> 18;
        int pix = tid & (NPIX - 1);
        int y   = pix >> 9;
        int x   = pix & (WW - 1);
        const float* tp0 = vf_pred + (size_t)b * 2 * NPIX;
        const float* tp1 = tp0 + NPIX;
        const float* tt0 = vf_true + (size_t)b * 2 * NPIX;
        const float* tt1 = tt0 + NPIX;
        float ptx = (float)x, pty = (float)y;
        float ppx = ptx,      ppy = pty;
        #pragma unroll
        for (int s = 0; s < NSTEPS; ++s) {
            float2 vt = bilerp2(tt0, tt1, ptx, pty);
            float2 vp = bilerp2(tp0, tp1, ppx, ppy);
            ptx += DXC * vt.x;  pty += DXC * vt.y;
            ppx += DXC * vp.x;  ppy += DXC * vp.y;
            float dx = ptx - ppx;
            float dy = pty - ppy;
            acc += dx * dx + dy * dy;
        }
    }
    double dacc = (double)acc;
    #pragma unroll
    for (int off = 32; off > 0; off >>= 1)
        dacc += __shfl_down(dacc, off, 64);
    __shared__ double sred[4];
    int lane = threadIdx.x & 63;
    int wid  = threadIdx.x >> 6;
    if (lane == 0) sred[wid] = dacc;
    __syncthreads();
    if (threadIdx.x == 0) {
        double t = sred[0] + sred[1] + sred[2] + sred[3];
        atomicAdd(ws_sum, t);
    }
}

__global__ void ivp_finalize_kernel(const double* __restrict__ ws_sum,
                                    float* __restrict__ out) {
    out[0] = (float)(ws_sum[0] / TOTAL_COUNT);
}

extern "C" void kernel_launch(void* const* d_in, const int* in_sizes, int n_in,
                              void* d_out, int out_size, void* d_ws, size_t ws_size,
                              hipStream_t stream) {
    const float* vf_pred = (const float*)d_in[0];
    const float* vf_true = (const float*)d_in[1];
    float* out = (float*)d_out;

    double* ws_sum = (double*)d_ws;
    hipMemsetAsync(ws_sum, 0, sizeof(double), stream);

    const size_t dup_bytes = (size_t)NTHREADS * sizeof(uint2);      // 16 MB per field
    const size_t need = 1024 + 2 * dup_bytes;                        // 32 MB + header

    if (ws_size >= need) {
        uint2* dupP = (uint2*)((char*)d_ws + 1024);
        uint2* dupT = (uint2*)((char*)d_ws + 1024 + dup_bytes);
        ivp_prep_kernel<<<NTHREADS / 256, 256, 0, stream>>>(vf_pred, vf_true, dupP, dupT);
        ivp_main_kernel<<<NTHREADS / 2 / 256, 256, 0, stream>>>(dupP, dupT, ws_sum);
    } else {
        ivp_loss_fallback_kernel<<<NTHREADS / 256, 256, 0, stream>>>(vf_pred, vf_true, ws_sum);
    }
    ivp_finalize_kernel<<<1, 1, 0, stream>>>(ws_sum, out);
}

// Round 4
// 73.231 us; speedup vs baseline: 2.4342x; 1.1386x over previous
//
#include <hip/hip_runtime.h>
#include <hip/hip_fp16.h>

#define DXC     0.5f
#define NSTEPS  8
#define BB      8
#define HH      512
#define WW      512
#define NPIX    (HH * WW)              // 262144
#define NTHREADS (BB * NPIX)           // 2097152
#define QQ      (NTHREADS / 4)         // 524288 pixels per chain-group
#define TOTAL_COUNT 37748736.0         // (NSTEPS+1) * B * 2 * H * W

typedef unsigned int u32;

__device__ __forceinline__ u32 packh2(float a, float b) {
    __half2 h = __floats2half2_rn(a, b);
    return __builtin_bit_cast(u32, h);
}

__device__ __forceinline__ float2 h2f2(u32 v) {
    __half2 h = __builtin_bit_cast(__half2, v);
    return make_float2(__low2float(h), __high2float(h));
}

// ---------------------------------------------------------------------------
// Prep: duplicated-interleaved fp16 layout per field (8 B per pixel):
//   dup[gpix] = uint2{ h2(vx(x),vy(x)), h2(vx(x+1),vy(x+1)) }  (x+1 clamped)
// Vectorized: 8 pixels/thread, float4 loads, uint4 stores.
// Also zeroes ws_sum (thread 0) so no separate memset dispatch is needed.
// ---------------------------------------------------------------------------
__device__ __forceinline__ void prep_field(const float* __restrict__ c0,
                                           const float* __restrict__ c1,
                                           uint4* __restrict__ out4,  // at this thread's slot
                                           int pixloc, int x) {
    float4 a0 = *(const float4*)(c0 + pixloc);
    float4 a1 = *(const float4*)(c0 + pixloc + 4);
    float4 b0 = *(const float4*)(c1 + pixloc);
    float4 b1 = *(const float4*)(c1 + pixloc + 4);
    int ei = pixloc + ((x == WW - 8) ? 7 : 8);
    float ae = c0[ei];
    float be = c1[ei];
    u32 h0 = packh2(a0.x, b0.x);
    u32 h1 = packh2(a0.y, b0.y);
    u32 h2 = packh2(a0.z, b0.z);
    u32 h3 = packh2(a0.w, b0.w);
    u32 h4 = packh2(a1.x, b1.x);
    u32 h5 = packh2(a1.y, b1.y);
    u32 h6 = packh2(a1.z, b1.z);
    u32 h7 = packh2(a1.w, b1.w);
    u32 h8 = packh2(ae, be);
    out4[0] = make_uint4(h0, h1, h1, h2);
    out4[1] = make_uint4(h2, h3, h3, h4);
    out4[2] = make_uint4(h4, h5, h5, h6);
    out4[3] = make_uint4(h6, h7, h7, h8);
}

__global__ __launch_bounds__(256) void ivp_prep_kernel(
        const float* __restrict__ vf_pred,
        const float* __restrict__ vf_true,
        uint4* __restrict__ dupP4,
        uint4* __restrict__ dupT4,
        double* __restrict__ ws_sum) {
    int t = blockIdx.x * 256 + threadIdx.x;        // 0..262143
    if (t == 0) ws_sum[0] = 0.0;
    int gp8    = t * 8;                            // global pixel index (8-aligned)
    int b      = gp8 >> 18;
    int pixloc = gp8 & (NPIX - 1);
    int x      = pixloc & (WW - 1);                // multiple of 8

    const float* p0 = vf_pred + (size_t)b * 2 * NPIX;
    const float* p1 = p0 + NPIX;
    const float* t0 = vf_true + (size_t)b * 2 * NPIX;
    const float* t1 = t0 + NPIX;

    prep_field(p0, p1, dupP4 + (gp8 >> 1), pixloc, x);
    prep_field(t0, t1, dupT4 + (gp8 >> 1), pixloc, x);
}

// ---------------------------------------------------------------------------
// Bilinear interp from the fp16 dup layout: 2x 8B loads, packed fp16 lerp.
// plane = b*NPIX (power-of-2 aligned, so plane|idx == plane+idx).
// ---------------------------------------------------------------------------
__device__ __forceinline__ float2 bilerp_h2(const uint2* __restrict__ dup,
                                            unsigned plane, float fx, float fy) {
    float x = fminf(fmaxf(fx, 0.0f), 511.0f);
    float y = fminf(fmaxf(fy, 0.0f), 511.0f);
    float xf = floorf(x), yf = floorf(y);
    int x0 = (int)xf, y0 = (int)yf;
    int y1 = min(y0 + 1, 511);
    unsigned i0 = plane | (unsigned)((y0 << 9) | x0);
    unsigned i1 = plane | (unsigned)((y1 << 9) | x0);
    uint2 r0 = dup[i0];
    uint2 r1 = dup[i1];
    __half2 wx = __float2half2_rn(x - xf);
    __half2 wy = __float2half2_rn(y - yf);
    __half2 a0 = __builtin_bit_cast(__half2, r0.x);
    __half2 a1 = __builtin_bit_cast(__half2, r0.y);
    __half2 b0 = __builtin_bit_cast(__half2, r1.x);
    __half2 b1 = __builtin_bit_cast(__half2, r1.y);
    __half2 rt = __hfma2(__hsub2(a1, a0), wx, a0);   // top row lerp
    __half2 rb = __hfma2(__hsub2(b1, b0), wx, b0);   // bottom row lerp
    __half2 v  = __hfma2(__hsub2(rb, rt), wy, rt);   // vertical lerp
    return make_float2(__low2float(v), __high2float(v));
}

// Main: 4 pixels per thread (8 independent Euler chains -> 16 loads in
// flight per step). Chunked XCD swizzle for L2 locality across steps.
__global__ __launch_bounds__(256) void ivp_main_kernel(
        const uint2* __restrict__ dupP,
        const uint2* __restrict__ dupT,
        double* __restrict__ ws_sum) {
    int bid = blockIdx.x;                          // 2048 blocks
    int lb  = (bid & 7) * (2048 / 8) + (bid >> 3);
    int tid = lb * 256 + threadIdx.x;              // 0..QQ-1

    float tx[4], ty[4], qx[4], qy[4];
    unsigned pl[4];
    #pragma unroll
    for (int k = 0; k < 4; ++k) {
        int p = tid + k * QQ;
        pl[k] = (unsigned)p & ~(unsigned)(NPIX - 1);   // b*NPIX
        int pix = p & (NPIX - 1);
        float fx = (float)(pix & (WW - 1));
        float fy = (float)(pix >> 9);
        tx[k] = qx[k] = fx;
        ty[k] = qy[k] = fy;
    }

    float acc = 0.0f;

    // Step 0: positions are exact lattice points -> direct 4B reads, no interp.
    #pragma unroll
    for (int k = 0; k < 4; ++k) {
        unsigned idx = (unsigned)(tid + k * QQ);
        float2 vt = h2f2(((const u32*)dupT)[2 * idx]);
        float2 vp = h2f2(((const u32*)dupP)[2 * idx]);
        tx[k] += DXC * vt.x;  ty[k] += DXC * vt.y;
        qx[k] += DXC * vp.x;  qy[k] += DXC * vp.y;
        float dx = tx[k] - qx[k], dy = ty[k] - qy[k];
        acc += dx * dx + dy * dy;
    }

    // Steps 1..7: bilinear gathers.
    #pragma unroll
    for (int s = 1; s < NSTEPS; ++s) {
        #pragma unroll
        for (int k = 0; k < 4; ++k) {
            float2 vt = bilerp_h2(dupT, pl[k], tx[k], ty[k]);
            float2 vp = bilerp_h2(dupP, pl[k], qx[k], qy[k]);
            tx[k] += DXC * vt.x;  ty[k] += DXC * vt.y;
            qx[k] += DXC * vp.x;  qy[k] += DXC * vp.y;
            float dx = tx[k] - qx[k], dy = ty[k] - qy[k];
            acc += dx * dx + dy * dy;
        }
    }

    // Wave-64 shuffle reduce in double, then LDS across 4 waves.
    double dacc = (double)acc;
    #pragma unroll
    for (int off = 32; off > 0; off >>= 1)
        dacc += __shfl_down(dacc, off, 64);

    __shared__ double sred[4];
    int lane = threadIdx.x & 63;
    int wid  = threadIdx.x >> 6;
    if (lane == 0) sred[wid] = dacc;
    __syncthreads();
    if (threadIdx.x == 0) {
        double tt = sred[0] + sred[1] + sred[2] + sred[3];
        atomicAdd(ws_sum, tt);
    }
}

// ---------------------------------------------------------------------------
// Fallback (R1 kernel) if ws_size can't hold the duplicated layout.
// ---------------------------------------------------------------------------
__device__ __forceinline__ float2 bilerp2(const float* __restrict__ vf0,
                                          const float* __restrict__ vf1,
                                          float px, float py) {
    float x = fminf(fmaxf(px, 0.0f), (float)(WW - 1));
    float y = fminf(fmaxf(py, 0.0f), (float)(HH - 1));
    float x0f = floorf(x);
    float y0f = floorf(y);
    float wx = x - x0f;
    float wy = y - y0f;
    int x0 = (int)x0f;
    int y0 = (int)y0f;
    int x1 = min(x0 + 1, WW - 1);
    int y1 = min(y0 + 1, HH - 1);
    int i00 = y0 * WW + x0;
    int i01 = y0 * WW + x1;
    int i10 = y1 * WW + x0;
    int i11 = y1 * WW + x1;
    float a00 = vf0[i00], a01 = vf0[i01], a10 = vf0[i10], a11 = vf0[i11];
    float b00 = vf1[i00], b01 = vf1[i01], b10 = vf1[i10], b11 = vf1[i11];
    float omwx = 1.0f - wx;
    float omwy = 1.0f - wy;
    float vx = (a00 * omwx + a01 * wx) * omwy + (a10 * omwx + a11 * wx) * wy;
    float vy = (b00 * omwx + b01 * wx) * omwy + (b10 * omwx + b11 * wx) * wy;
    return make_float2(vx, vy);
}

__global__ __launch_bounds__(256) void ivp_loss_fallback_kernel(
        const float* __restrict__ vf_pred,
        const float* __restrict__ vf_true,
        double* __restrict__ ws_sum) {
    int tid = blockIdx.x * blockDim.x + threadIdx.x;
    float acc = 0.0f;
    {
        int b   = tid >> 18;
        int pix = tid & (NPIX - 1);
        int y   = pix >> 9;
        int x   = pix & (WW - 1);
        const float* tp0 = vf_pred + (size_t)b * 2 * NPIX;
        const float* tp1 = tp0 + NPIX;
        const float* tt0 = vf_true + (size_t)b * 2 * NPIX;
        const float* tt1 = tt0 + NPIX;
        float ptx = (float)x, pty = (float)y;
        float ppx = ptx,      ppy = pty;
        #pragma unroll
        for (int s = 0; s < NSTEPS; ++s) {
            float2 vt = bilerp2(tt0, tt1, ptx, pty);
            float2 vp = bilerp2(tp0, tp1, ppx, ppy);
            ptx += DXC * vt.x;  pty += DXC * vt.y;
            ppx += DXC * vp.x;  ppy += DXC * vp.y;
            float dx = ptx - ppx;
            float dy = pty - ppy;
            acc += dx * dx + dy * dy;
        }
    }
    double dacc = (double)acc;
    #pragma unroll
    for (int off = 32; off > 0; off >>= 1)
        dacc += __shfl_down(dacc, off, 64);
    __shared__ double sred[4];
    int lane = threadIdx.x & 63;
    int wid  = threadIdx.x >> 6;
    if (lane == 0) sred[wid] = dacc;
    __syncthreads();
    if (threadIdx.x == 0) {
        double t = sred[0] + sred[1] + sred[2] + sred[3];
        atomicAdd(ws_sum, t);
    }
}

__global__ void ivp_finalize_kernel(const double* __restrict__ ws_sum,
                                    float* __restrict__ out) {
    out[0] = (float)(ws_sum[0] / TOTAL_COUNT);
}

extern "C" void kernel_launch(void* const* d_in, const int* in_sizes, int n_in,
                              void* d_out, int out_size, void* d_ws, size_t ws_size,
                              hipStream_t stream) {
    const float* vf_pred = (const float*)d_in[0];
    const float* vf_true = (const float*)d_in[1];
    float* out = (float*)d_out;
    double* ws_sum = (double*)d_ws;

    const size_t dup_bytes = (size_t)NTHREADS * sizeof(uint2);      // 16 MB per field
    const size_t need = 1024 + 2 * dup_bytes;                        // 32 MB + header

    if (ws_size >= need) {
        char* base = (char*)d_ws;
        uint4* dupP4 = (uint4*)(base + 1024);
        uint4* dupT4 = (uint4*)(base + 1024 + dup_bytes);
        ivp_prep_kernel<<<NTHREADS / 8 / 256, 256, 0, stream>>>(
            vf_pred, vf_true, dupP4, dupT4, ws_sum);
        ivp_main_kernel<<<QQ / 256, 256, 0, stream>>>(
            (const uint2*)dupP4, (const uint2*)dupT4, ws_sum);
    } else {
        hipMemsetAsync(ws_sum, 0, sizeof(double), stream);
        ivp_loss_fallback_kernel<<<NTHREADS / 256, 256, 0, stream>>>(
            vf_pred, vf_true, ws_sum);
    }
    ivp_finalize_kernel<<<1, 1, 0, stream>>>(ws_sum, out);
}

// Round 5
// 58.141 us; speedup vs baseline: 3.0660x; 1.2595x over previous
//
#include <hip/hip_runtime.h>
#include <hip/hip_fp16.h>

#define DXC     0.5f
#define NSTEPS  8
#define BB      8
#define HH      512
#define WW      512
#define NPIX    (HH * WW)              // 262144
#define NTHREADS (BB * NPIX)           // 2097152
#define TOTAL_COUNT 37748736.0         // (NSTEPS+1) * B * 2 * H * W

typedef unsigned int u32;

__device__ __forceinline__ u32 packh2(float a, float b) {
    __half2 h = __floats2half2_rn(a, b);
    return __builtin_bit_cast(u32, h);
}

__device__ __forceinline__ float2 h2f2(u32 v) {
    __half2 h = __builtin_bit_cast(__half2, v);
    return make_float2(__low2float(h), __high2float(h));
}

// ---------------------------------------------------------------------------
// Prep: duplicated-interleaved fp16 layout per field (8 B per pixel):
//   dup[gpix] = uint2{ h2(vx(x),vy(x)), h2(vx(x+1),vy(x+1)) }  (x+1 clamped)
// Vectorized: 8 pixels/thread, float4 loads, uint4 stores.
// Also zeroes ws_sum (thread 0).
// ---------------------------------------------------------------------------
__device__ __forceinline__ void prep_field(const float* __restrict__ c0,
                                           const float* __restrict__ c1,
                                           uint4* __restrict__ out4,
                                           int pixloc, int x) {
    float4 a0 = *(const float4*)(c0 + pixloc);
    float4 a1 = *(const float4*)(c0 + pixloc + 4);
    float4 b0 = *(const float4*)(c1 + pixloc);
    float4 b1 = *(const float4*)(c1 + pixloc + 4);
    int ei = pixloc + ((x == WW - 8) ? 7 : 8);
    float ae = c0[ei];
    float be = c1[ei];
    u32 h0 = packh2(a0.x, b0.x);
    u32 h1 = packh2(a0.y, b0.y);
    u32 h2 = packh2(a0.z, b0.z);
    u32 h3 = packh2(a0.w, b0.w);
    u32 h4 = packh2(a1.x, b1.x);
    u32 h5 = packh2(a1.y, b1.y);
    u32 h6 = packh2(a1.z, b1.z);
    u32 h7 = packh2(a1.w, b1.w);
    u32 h8 = packh2(ae, be);
    out4[0] = make_uint4(h0, h1, h1, h2);
    out4[1] = make_uint4(h2, h3, h3, h4);
    out4[2] = make_uint4(h4, h5, h5, h6);
    out4[3] = make_uint4(h6, h7, h7, h8);
}

__global__ __launch_bounds__(256) void ivp_prep_kernel(
        const float* __restrict__ vf_pred,
        const float* __restrict__ vf_true,
        uint4* __restrict__ dupP4,
        uint4* __restrict__ dupT4,
        double* __restrict__ ws_sum) {
    int t = blockIdx.x * 256 + threadIdx.x;        // 0..262143
    if (t == 0) ws_sum[0] = 0.0;
    int gp8    = t * 8;
    int b      = gp8 >> 18;
    int pixloc = gp8 & (NPIX - 1);
    int x      = pixloc & (WW - 1);

    const float* p0 = vf_pred + (size_t)b * 2 * NPIX;
    const float* p1 = p0 + NPIX;
    const float* t0 = vf_true + (size_t)b * 2 * NPIX;
    const float* t1 = t0 + NPIX;

    prep_field(p0, p1, dupP4 + (gp8 >> 1), pixloc, x);
    prep_field(t0, t1, dupT4 + (gp8 >> 1), pixloc, x);
}

// ---------------------------------------------------------------------------
// Tile gather: clamped-LDS fast path + exec-masked global fixup for escapees.
// tile = 64x64 uint2 entries staged from dup with edge replication, so
// r1 = tile[e+64] is correct without a y1 clamp in tile coords.
// ---------------------------------------------------------------------------
__device__ __forceinline__ float2 gather_tile(const uint2* tile,
                                              const uint2* __restrict__ gdup,
                                              unsigned plane, int tx0m, int ty0m,
                                              float fx, float fy) {
    float x = fminf(fmaxf(fx, 0.0f), 511.0f);
    float y = fminf(fmaxf(fy, 0.0f), 511.0f);
    unsigned xi = (unsigned)x;          // trunc == floor (x >= 0)
    unsigned yi = (unsigned)y;
    float wxf = x - (float)xi;
    float wyf = y - (float)yi;
    int lx = (int)xi - tx0m;
    int ly = (int)yi - ty0m;
    bool inh = ((unsigned)lx < 64u) && ((unsigned)ly < 63u);
    int clx = min(max(lx, 0), 63);
    int cly = min(max(ly, 0), 62);
    int e = (cly << 6) | clx;
    uint2 r0 = tile[e];
    uint2 r1 = tile[e + 64];
    if (!inh) {                          // rare: execz-skipped nearly always
        unsigned i0 = plane | (yi << 9) | xi;
        unsigned y1 = min(yi + 1u, 511u);
        unsigned i1 = plane | (y1 << 9) | xi;
        r0 = gdup[i0];
        r1 = gdup[i1];
    }
    __half2 wx = __float2half2_rn(wxf);
    __half2 wy = __float2half2_rn(wyf);
    __half2 a0 = __builtin_bit_cast(__half2, r0.x);
    __half2 a1 = __builtin_bit_cast(__half2, r0.y);
    __half2 b0 = __builtin_bit_cast(__half2, r1.x);
    __half2 b1 = __builtin_bit_cast(__half2, r1.y);
    __half2 rt = __hfma2(__hsub2(a1, a0), wx, a0);
    __half2 rb = __hfma2(__hsub2(b1, b0), wx, b0);
    __half2 v  = __hfma2(__hsub2(rb, rt), wy, rt);
    return make_float2(__low2float(v), __high2float(v));
}

// Main: one 32x32 pixel tile per 1024-thread block; both fields' 64x64 halo'd
// regions staged in LDS (64 KB -> 2 blocks/CU, 32 waves/CU). batch = bid&7
// keeps each batch's 4 MB dup footprint on one XCD's L2.
__global__ __launch_bounds__(1024, 8) void ivp_main_tile(
        const uint2* __restrict__ dupP,
        const uint2* __restrict__ dupT,
        double* __restrict__ ws_sum) {
    __shared__ uint2 tileT[4096];
    __shared__ uint2 tileP[4096];
    __shared__ double sred[16];

    int bid   = blockIdx.x;            // 2048 blocks
    int batch = bid & 7;
    int tile  = bid >> 3;              // 0..255 within batch
    int tx0   = (tile & 15) << 5;
    int ty0   = (tile >> 4) << 5;
    int tx0m  = tx0 - 16;
    int ty0m  = ty0 - 16;
    unsigned plane = (unsigned)batch << 18;
    int t = threadIdx.x;

    // Stage 64x64 halo'd region of both fields (edge-replicated).
    #pragma unroll
    for (int i = 0; i < 4; ++i) {
        int e  = t + i * 1024;
        int ly = e >> 6, lx = e & 63;
        int gy = min(max(ty0m + ly, 0), 511);
        int gx = min(max(tx0m + lx, 0), 511);
        unsigned gi = plane | (unsigned)((gy << 9) | gx);
        tileT[e] = dupT[gi];
        tileP[e] = dupP[gi];
    }
    __syncthreads();

    float txp = (float)(tx0 + (t & 31));   // true-chain pos
    float typ = (float)(ty0 + (t >> 5));
    float pxp = txp, pyp = typ;            // pred-chain pos

    float acc = 0.0f;

    // Step 0: exact lattice point -> direct LDS read, no interp.
    {
        int e0 = (((t >> 5) + 16) << 6) | ((t & 31) + 16);
        float2 vt = h2f2(tileT[e0].x);
        float2 vp = h2f2(tileP[e0].x);
        txp += DXC * vt.x;  typ += DXC * vt.y;
        pxp += DXC * vp.x;  pyp += DXC * vp.y;
        float dx = txp - pxp, dy = typ - pyp;
        acc += dx * dx + dy * dy;
    }

    // Steps 1..7.
    #pragma unroll
    for (int s = 1; s < NSTEPS; ++s) {
        float2 vt = gather_tile(tileT, dupT, plane, tx0m, ty0m, txp, typ);
        float2 vp = gather_tile(tileP, dupP, plane, tx0m, ty0m, pxp, pyp);
        txp += DXC * vt.x;  typ += DXC * vt.y;
        pxp += DXC * vp.x;  pyp += DXC * vp.y;
        float dx = txp - pxp, dy = typ - pyp;
        acc += dx * dx + dy * dy;
    }

    // Reduce: wave-64 shuffle in double, LDS across 16 waves, one atomic.
    double dacc = (double)acc;
    #pragma unroll
    for (int off = 32; off > 0; off >>= 1)
        dacc += __shfl_down(dacc, off, 64);

    int lane = t & 63;
    int wid  = t >> 6;
    if (lane == 0) sred[wid] = dacc;
    __syncthreads();
    if (t == 0) {
        double s = 0.0;
        #pragma unroll
        for (int w = 0; w < 16; ++w) s += sred[w];
        atomicAdd(ws_sum, s);
    }
}

// ---------------------------------------------------------------------------
// Fallback (R1 kernel) if ws_size can't hold the duplicated layout.
// ---------------------------------------------------------------------------
__device__ __forceinline__ float2 bilerp2(const float* __restrict__ vf0,
                                          const float* __restrict__ vf1,
                                          float px, float py) {
    float x = fminf(fmaxf(px, 0.0f), (float)(WW - 1));
    float y = fminf(fmaxf(py, 0.0f), (float)(HH - 1));
    float x0f = floorf(x);
    float y0f = floorf(y);
    float wx = x - x0f;
    float wy = y - y0f;
    int x0 = (int)x0f;
    int y0 = (int)y0f;
    int x1 = min(x0 + 1, WW - 1);
    int y1 = min(y0 + 1, HH - 1);
    int i00 = y0 * WW + x0;
    int i01 = y0 * WW + x1;
    int i10 = y1 * WW + x0;
    int i11 = y1 * WW + x1;
    float a00 = vf0[i00], a01 = vf0[i01], a10 = vf0[i10], a11 = vf0[i11];
    float b00 = vf1[i00], b01 = vf1[i01], b10 = vf1[i10], b11 = vf1[i11];
    float omwx = 1.0f - wx;
    float omwy = 1.0f - wy;
    float vx = (a00 * omwx + a01 * wx) * omwy + (a10 * omwx + a11 * wx) * wy;
    float vy = (b00 * omwx + b01 * wx) * omwy + (b10 * omwx + b11 * wx) * wy;
    return make_float2(vx, vy);
}

__global__ __launch_bounds__(256) void ivp_loss_fallback_kernel(
        const float* __restrict__ vf_pred,
        const float* __restrict__ vf_true,
        double* __restrict__ ws_sum) {
    int tid = blockIdx.x * blockDim.x + threadIdx.x;
    float acc = 0.0f;
    {
        int b   = tid >> 18;
        int pix = tid & (NPIX - 1);
        int y   = pix >> 9;
        int x   = pix & (WW - 1);
        const float* tp0 = vf_pred + (size_t)b * 2 * NPIX;
        const float* tp1 = tp0 + NPIX;
        const float* tt0 = vf_true + (size_t)b * 2 * NPIX;
        const float* tt1 = tt0 + NPIX;
        float ptx = (float)x, pty = (float)y;
        float ppx = ptx,      ppy = pty;
        #pragma unroll
        for (int s = 0; s < NSTEPS; ++s) {
            float2 vt = bilerp2(tt0, tt1, ptx, pty);
            float2 vp = bilerp2(tp0, tp1, ppx, ppy);
            ptx += DXC * vt.x;  pty += DXC * vt.y;
            ppx += DXC * vp.x;  ppy += DXC * vp.y;
            float dx = ptx - ppx;
            float dy = pty - ppy;
            acc += dx * dx + dy * dy;
        }
    }
    double dacc = (double)acc;
    #pragma unroll
    for (int off = 32; off > 0; off >>= 1)
        dacc += __shfl_down(dacc, off, 64);
    __shared__ double sred[4];
    int lane = threadIdx.x & 63;
    int wid  = threadIdx.x >> 6;
    if (lane == 0) sred[wid] = dacc;
    __syncthreads();
    if (threadIdx.x == 0) {
        double t = sred[0] + sred[1] + sred[2] + sred[3];
        atomicAdd(ws_sum, t);
    }
}

__global__ void ivp_finalize_kernel(const double* __restrict__ ws_sum,
                                    float* __restrict__ out) {
    out[0] = (float)(ws_sum[0] / TOTAL_COUNT);
}

extern "C" void kernel_launch(void* const* d_in, const int* in_sizes, int n_in,
                              void* d_out, int out_size, void* d_ws, size_t ws_size,
                              hipStream_t stream) {
    const float* vf_pred = (const float*)d_in[0];
    const float* vf_true = (const float*)d_in[1];
    float* out = (float*)d_out;
    double* ws_sum = (double*)d_ws;

    const size_t dup_bytes = (size_t)NTHREADS * sizeof(uint2);      // 16 MB per field
    const size_t need = 1024 + 2 * dup_bytes;                        // 32 MB + header

    if (ws_size >= need) {
        char* base = (char*)d_ws;
        uint4* dupP4 = (uint4*)(base + 1024);
        uint4* dupT4 = (uint4*)(base + 1024 + dup_bytes);
        ivp_prep_kernel<<<NTHREADS / 8 / 256, 256, 0, stream>>>(
            vf_pred, vf_true, dupP4, dupT4, ws_sum);
        ivp_main_tile<<<2048, 1024, 0, stream>>>(
            (const uint2*)dupP4, (const uint2*)dupT4, ws_sum);
    } else {
        hipMemsetAsync(ws_sum, 0, sizeof(double), stream);
        ivp_loss_fallback_kernel<<<NTHREADS / 256, 256, 0, stream>>>(
            vf_pred, vf_true, ws_sum);
    }
    ivp_finalize_kernel<<<1, 1, 0, stream>>>(ws_sum, out);
}

// Round 6
// 49.924 us; speedup vs baseline: 3.5707x; 1.1646x over previous
//
#include <hip/hip_runtime.h>
#include <hip/hip_fp16.h>

#define DXC     0.5f
#define NSTEPS  8
#define BB      8
#define HH      512
#define WW      512
#define NPIX    (HH * WW)              // 262144
#define NTHREADS (BB * NPIX)           // 2097152
#define TOTAL_COUNT 37748736.0         // (NSTEPS+1) * B * 2 * H * W

#define TSTRIDE 65                     // padded LDS row stride (u32 entries)
#define TMAX    (63 * TSTRIDE + 62)    // max legal fast-path e (reads +66 ok)

typedef unsigned int u32;

__device__ __forceinline__ u32 packh2(float a, float b) {
    __half2 h = __floats2half2_rn(a, b);
    return __builtin_bit_cast(u32, h);
}

__device__ __forceinline__ float2 h2f2(u32 v) {
    __half2 h = __builtin_bit_cast(__half2, v);
    return make_float2(__low2float(h), __high2float(h));
}

// ---------------------------------------------------------------------------
// Prep: compact fp16 layout per field (4 B per pixel): dup32[gpix]=h2(vx,vy).
// 8 px/thread, float4 loads, uint4 stores. Thread 0 zeroes ws_sum.
// ---------------------------------------------------------------------------
__global__ __launch_bounds__(256) void ivp_prep_kernel(
        const float* __restrict__ vf_pred,
        const float* __restrict__ vf_true,
        u32* __restrict__ dupP32,
        u32* __restrict__ dupT32,
        double* __restrict__ ws_sum) {
    int t = blockIdx.x * 256 + threadIdx.x;        // 0..262143
    if (t == 0) ws_sum[0] = 0.0;
    int gp8    = t * 8;
    int b      = gp8 >> 18;
    int pixloc = gp8 & (NPIX - 1);

    {
        const float* c0 = vf_pred + (size_t)b * 2 * NPIX;
        const float* c1 = c0 + NPIX;
        float4 a0 = *(const float4*)(c0 + pixloc);
        float4 a1 = *(const float4*)(c0 + pixloc + 4);
        float4 b0 = *(const float4*)(c1 + pixloc);
        float4 b1 = *(const float4*)(c1 + pixloc + 4);
        uint4 o0 = make_uint4(packh2(a0.x, b0.x), packh2(a0.y, b0.y),
                              packh2(a0.z, b0.z), packh2(a0.w, b0.w));
        uint4 o1 = make_uint4(packh2(a1.x, b1.x), packh2(a1.y, b1.y),
                              packh2(a1.z, b1.z), packh2(a1.w, b1.w));
        ((uint4*)(dupP32 + gp8))[0] = o0;
        ((uint4*)(dupP32 + gp8))[1] = o1;
    }
    {
        const float* c0 = vf_true + (size_t)b * 2 * NPIX;
        const float* c1 = c0 + NPIX;
        float4 a0 = *(const float4*)(c0 + pixloc);
        float4 a1 = *(const float4*)(c0 + pixloc + 4);
        float4 b0 = *(const float4*)(c1 + pixloc);
        float4 b1 = *(const float4*)(c1 + pixloc + 4);
        uint4 o0 = make_uint4(packh2(a0.x, b0.x), packh2(a0.y, b0.y),
                              packh2(a0.z, b0.z), packh2(a0.w, b0.w));
        uint4 o1 = make_uint4(packh2(a1.x, b1.x), packh2(a1.y, b1.y),
                              packh2(a1.z, b1.z), packh2(a1.w, b1.w));
        ((uint4*)(dupT32 + gp8))[0] = o0;
        ((uint4*)(dupT32 + gp8))[1] = o1;
    }
}

// ---------------------------------------------------------------------------
// Gather in tile-local coordinates.
//   x_loc = global_x - tx0m  (tx0m = tile origin minus halo), clamped to the
//   GLOBAL domain expressed locally ([xlo,xhi] in VGPRs).
//   Weights wx = x_loc - floor(x_loc) are translation-invariant -> exact for
//   both the LDS fast path and the rare global fixup path.
// ---------------------------------------------------------------------------
__device__ __forceinline__ float2 gather_tile(const u32* tile,
                                              const u32* __restrict__ gdup,
                                              unsigned plane, int tx0m, int ty0m,
                                              float xlo, float xhi,
                                              float ylo, float yhi,
                                              float fx, float fy) {
    float x = fminf(fmaxf(fx, xlo), xhi);      // v_med3_f32
    float y = fminf(fmaxf(fy, ylo), yhi);
    float lxf = floorf(x);
    float lyf = floorf(y);
    float wxf = x - lxf;
    float wyf = y - lyf;
    int lx = (int)lxf;                          // exact: trunc of floored
    int ly = (int)lyf;
    bool inh = ((unsigned)lx < 63u) && ((unsigned)ly < 63u);
    unsigned e = min((unsigned)(ly * TSTRIDE + lx), (unsigned)TMAX);
    u32 c00 = tile[e];
    u32 c01 = tile[e + 1];                      // merged -> ds_read2_b32
    u32 c10 = tile[e + TSTRIDE];
    u32 c11 = tile[e + TSTRIDE + 1];
    if (!inh) {                                 // rare: execz-skipped
        int gx0 = lx + tx0m;                    // in [0,511] by construction
        int gy0 = ly + ty0m;
        int gx1 = min(gx0 + 1, 511);
        int gy1 = min(gy0 + 1, 511);
        unsigned r0b = plane | (unsigned)(gy0 << 9);
        unsigned r1b = plane | (unsigned)(gy1 << 9);
        c00 = gdup[r0b | (unsigned)gx0];
        c01 = gdup[r0b | (unsigned)gx1];
        c10 = gdup[r1b | (unsigned)gx0];
        c11 = gdup[r1b | (unsigned)gx1];
    }
    __half2 wx = __float2half2_rn(wxf);
    __half2 wy = __float2half2_rn(wyf);
    __half2 a0 = __builtin_bit_cast(__half2, c00);
    __half2 a1 = __builtin_bit_cast(__half2, c01);
    __half2 b0 = __builtin_bit_cast(__half2, c10);
    __half2 b1 = __builtin_bit_cast(__half2, c11);
    __half2 rt = __hfma2(__hsub2(a1, a0), wx, a0);
    __half2 rb = __hfma2(__hsub2(b1, b0), wx, b0);
    __half2 v  = __hfma2(__hsub2(rb, rt), wy, rt);
    return make_float2(__low2float(v), __high2float(v));
}

// Main: one 32x32 pixel tile per 1024-thread block; both fields' 64x64 halo'd
// regions staged compact in LDS (~34 KB). batch = bid&7 -> XCD L2 affinity.
__global__ __launch_bounds__(1024, 8) void ivp_main_tile(
        const u32* __restrict__ dupP,
        const u32* __restrict__ dupT,
        double* __restrict__ ws_sum) {
    __shared__ u32 tileT[64 * TSTRIDE + 8];
    __shared__ u32 tileP[64 * TSTRIDE + 8];
    __shared__ double sred[16];

    int bid   = blockIdx.x;            // 2048 blocks
    int batch = bid & 7;
    int tile  = bid >> 3;              // 0..255 within batch
    int tx0   = (tile & 15) << 5;
    int ty0   = (tile >> 4) << 5;
    int tx0m  = tx0 - 16;
    int ty0m  = ty0 - 16;
    unsigned plane = (unsigned)batch << 18;
    int t = threadIdx.x;

    // Global clamp bounds in local coordinates (VGPR-resident).
    float xlo = (float)(-tx0m), xhi = (float)(511 - tx0m);
    float ylo = (float)(-ty0m), yhi = (float)(511 - ty0m);

    // Stage 64x64 halo'd region of both fields (edge-replicated).
    #pragma unroll
    for (int i = 0; i < 4; ++i) {
        int e  = t + i * 1024;
        int ly = e >> 6, lx = e & 63;
        int gy = min(max(ty0m + ly, 0), 511);
        int gx = min(max(tx0m + lx, 0), 511);
        unsigned gi = plane | (unsigned)((gy << 9) | gx);
        int le = ly * TSTRIDE + lx;
        tileT[le] = dupT[gi];
        tileP[le] = dupP[gi];
    }
    __syncthreads();

    // Positions in tile-local coords (global - (tx0m,ty0m)).
    float txp = (float)((t & 31) + 16);
    float typ = (float)((t >> 5) + 16);
    float pxp = txp, pyp = typ;

    float acc = 0.0f;

    // Step 0: exact lattice point -> direct LDS read, no interp.
    {
        int e0 = ((t >> 5) + 16) * TSTRIDE + ((t & 31) + 16);
        float2 vt = h2f2(tileT[e0]);
        float2 vp = h2f2(tileP[e0]);
        txp += DXC * vt.x;  typ += DXC * vt.y;
        pxp += DXC * vp.x;  pyp += DXC * vp.y;
        float dx = txp - pxp, dy = typ - pyp;
        acc += dx * dx + dy * dy;
    }

    // Steps 1..7.
    #pragma unroll
    for (int s = 1; s < NSTEPS; ++s) {
        float2 vt = gather_tile(tileT, dupT, plane, tx0m, ty0m,
                                xlo, xhi, ylo, yhi, txp, typ);
        float2 vp = gather_tile(tileP, dupP, plane, tx0m, ty0m,
                                xlo, xhi, ylo, yhi, pxp, pyp);
        txp += DXC * vt.x;  typ += DXC * vt.y;
        pxp += DXC * vp.x;  pyp += DXC * vp.y;
        float dx = txp - pxp, dy = typ - pyp;
        acc += dx * dx + dy * dy;
    }

    // Reduce: wave-64 shuffle in double, LDS across 16 waves, one atomic.
    double dacc = (double)acc;
    #pragma unroll
    for (int off = 32; off > 0; off >>= 1)
        dacc += __shfl_down(dacc, off, 64);

    int lane = t & 63;
    int wid  = t >> 6;
    if (lane == 0) sred[wid] = dacc;
    __syncthreads();
    if (t == 0) {
        double s = 0.0;
        #pragma unroll
        for (int w = 0; w < 16; ++w) s += sred[w];
        atomicAdd(ws_sum, s);
    }
}

// ---------------------------------------------------------------------------
// Fallback (R1 kernel) if ws_size can't hold the compact layout.
// ---------------------------------------------------------------------------
__device__ __forceinline__ float2 bilerp2(const float* __restrict__ vf0,
                                          const float* __restrict__ vf1,
                                          float px, float py) {
    float x = fminf(fmaxf(px, 0.0f), (float)(WW - 1));
    float y = fminf(fmaxf(py, 0.0f), (float)(HH - 1));
    float x0f = floorf(x);
    float y0f = floorf(y);
    float wx = x - x0f;
    float wy = y - y0f;
    int x0 = (int)x0f;
    int y0 = (int)y0f;
    int x1 = min(x0 + 1, WW - 1);
    int y1 = min(y0 + 1, HH - 1);
    int i00 = y0 * WW + x0;
    int i01 = y0 * WW + x1;
    int i10 = y1 * WW + x0;
    int i11 = y1 * WW + x1;
    float a00 = vf0[i00], a01 = vf0[i01], a10 = vf0[i10], a11 = vf0[i11];
    float b00 = vf1[i00], b01 = vf1[i01], b10 = vf1[i10], b11 = vf1[i11];
    float omwx = 1.0f - wx;
    float omwy = 1.0f - wy;
    float vx = (a00 * omwx + a01 * wx) * omwy + (a10 * omwx + a11 * wx) * wy;
    float vy = (b00 * omwx + b01 * wx) * omwy + (b10 * omwx + b11 * wx) * wy;
    return make_float2(vx, vy);
}

__global__ __launch_bounds__(256) void ivp_loss_fallback_kernel(
        const float* __restrict__ vf_pred,
        const float* __restrict__ vf_true,
        double* __restrict__ ws_sum) {
    int tid = blockIdx.x * blockDim.x + threadIdx.x;
    float acc = 0.0f;
    {
        int b   = tid >> 18;
        int pix = tid & (NPIX - 1);
        int y   = pix >> 9;
        int x   = pix & (WW - 1);
        const float* tp0 = vf_pred + (size_t)b * 2 * NPIX;
        const float* tp1 = tp0 + NPIX;
        const float* tt0 = vf_true + (size_t)b * 2 * NPIX;
        const float* tt1 = tt0 + NPIX;
        float ptx = (float)x, pty = (float)y;
        float ppx = ptx,      ppy = pty;
        #pragma unroll
        for (int s = 0; s < NSTEPS; ++s) {
            float2 vt = bilerp2(tt0, tt1, ptx, pty);
            float2 vp = bilerp2(tp0, tp1, ppx, ppy);
            ptx += DXC * vt.x;  pty += DXC * vt.y;
            ppx += DXC * vp.x;  ppy += DXC * vp.y;
            float dx = ptx - ppx;
            float dy = pty - ppy;
            acc += dx * dx + dy * dy;
        }
    }
    double dacc = (double)acc;
    #pragma unroll
    for (int off = 32; off > 0; off >>= 1)
        dacc += __shfl_down(dacc, off, 64);
    __shared__ double sred[4];
    int lane = threadIdx.x & 63;
    int wid  = threadIdx.x >> 6;
    if (lane == 0) sred[wid] = dacc;
    __syncthreads();
    if (threadIdx.x == 0) {
        double t = sred[0] + sred[1] + sred[2] + sred[3];
        atomicAdd(ws_sum, t);
    }
}

__global__ void ivp_finalize_kernel(const double* __restrict__ ws_sum,
                                    float* __restrict__ out) {
    out[0] = (float)(ws_sum[0] / TOTAL_COUNT);
}

extern "C" void kernel_launch(void* const* d_in, const int* in_sizes, int n_in,
                              void* d_out, int out_size, void* d_ws, size_t ws_size,
                              hipStream_t stream) {
    const float* vf_pred = (const float*)d_in[0];
    const float* vf_true = (const float*)d_in[1];
    float* out = (float*)d_out;
    double* ws_sum = (double*)d_ws;

    const size_t dup_bytes = (size_t)NTHREADS * sizeof(u32);        // 8 MB per field
    const size_t need = 1024 + 2 * dup_bytes;                        // 16 MB + header

    if (ws_size >= need) {
        char* base = (char*)d_ws;
        u32* dupP32 = (u32*)(base + 1024);
        u32* dupT32 = (u32*)(base + 1024 + dup_bytes);
        ivp_prep_kernel<<<NTHREADS / 8 / 256, 256, 0, stream>>>(
            vf_pred, vf_true, dupP32, dupT32, ws_sum);
        ivp_main_tile<<<2048, 1024, 0, stream>>>(dupP32, dupT32, ws_sum);
    } else {
        hipMemsetAsync(ws_sum, 0, sizeof(double), stream);
        ivp_loss_fallback_kernel<<<NTHREADS / 256, 256, 0, stream>>>(
            vf_pred, vf_true, ws_sum);
    }
    ivp_finalize_kernel<<<1, 1, 0, stream>>>(ws_sum, out);
}